// Round 7
// baseline (18333.472 us; speedup 1.0000x reference)
//
#include <hip/hip_runtime.h>
#include <hip/hip_bf16.h>
#include <math.h>

// HMM forward: alpha_t = (alpha_{t-1} @ A) * B[:, se[t]],  out = -log(sum(alpha_{T-1}))
// N_STATES=2048, N_OBS=8192, T=8192.
//
// Persistent kernel, 64 blk x 512 thr. A in 128 f32 regs/thread (pinned).
// Sync = per-block FLAG + untagged data (this round's change):
//   publisher: 32 u32 data stores -> vmcnt(0) -> flag[blk]=t (all agent-scope
//   relaxed atomics, LLC-direct, no cache maintenance).
//   reader wave: spin on its 8 source flags (8 loads/iter vs 256 in the old
//   per-packet tag scheme -> 32x less LLC poll pressure), then ONE data gather.
// Parity double-buffer safe: every block observes all 64 flags each step,
// so flag=t+1 everywhere implies all step-t readers are done (skew <= 1).

#define NS    2048
#define NOBS  8192
#define TSEQ  8192
#define NBLK  64
#define NTHR  512
#define OPB   32              // output columns per block
#define JPT   128             // j-slice length per thread
#define FSTR  32              // u32 stride between flags (128B padding)

typedef unsigned long long u64;
typedef unsigned int u32;

// X-macro over the 32 float4 A-fragments
#define A_LIST(X) \
  X(0)  X(1)  X(2)  X(3)  X(4)  X(5)  X(6)  X(7)  \
  X(8)  X(9)  X(10) X(11) X(12) X(13) X(14) X(15) \
  X(16) X(17) X(18) X(19) X(20) X(21) X(22) X(23) \
  X(24) X(25) X(26) X(27) X(28) X(29) X(30) X(31)

__global__ void __launch_bounds__(256) init_ws_kernel(u32* flags) {
  const int i = threadIdx.x;     // 1 block x 256 threads; 64 slots x 32 u32 = 2048
#pragma unroll
  for (int c = 0; c < 8; ++c) {
    __hip_atomic_store(&flags[i * 8 + c], 0u, __ATOMIC_RELAXED, __HIP_MEMORY_SCOPE_AGENT);
  }
}

__global__ void __launch_bounds__(NTHR, 2) hmm_forward_kernel(
    const float* __restrict__ Pi0,
    const float* __restrict__ A,
    const float* __restrict__ B,
    const int*   __restrict__ se,
    float* __restrict__ out,
    u32*   __restrict__ aGd,           // [2][NS] alpha payload (f32 bits)
    u32*   __restrict__ flags) {       // [NBLK] step flags, FSTR-padded
  __shared__ __align__(16) float alpha_sm[NS];
  __shared__ float red[2][NTHR / 64][OPB];   // [parity][wave][o] (conflict-free)

  const int tid    = threadIdx.x;
  const int blk    = blockIdx.x;
  const int w      = tid >> 6;       // wave 0..7
  const int lane   = tid & 63;
  const int h      = lane >> 5;      // half-wave
  const int o      = lane & 31;      // output slot within block
  const int i_mine = blk * OPB + o;  // owned output column
  const int jbase  = (w * 2 + h) * JPT;

  // ---- A column-slice into 32 named float4 SSA registers:
  //      Ar{k} = A[jbase+4k .. jbase+4k+3][i_mine]
#define DECLA(k) float4 Ar##k;
  A_LIST(DECLA)
#define LOADA(k) { const float* ap = A + (size_t)(jbase + 4 * k) * NS + i_mine; \
                   Ar##k.x = ap[0]; Ar##k.y = ap[NS]; Ar##k.z = ap[2 * NS]; Ar##k.w = ap[3 * NS]; }
  A_LIST(LOADA)
  // Opaque pin: asm-defined scalars cannot be refolded/remat'd into the loop.
#define PIN4(k) asm volatile("" : "+v"(Ar##k.x), "+v"(Ar##k.y), "+v"(Ar##k.z), "+v"(Ar##k.w));
  A_LIST(PIN4)

  // ---- alpha_0 = Pi0 * B[:, se[0]], computed redundantly by every block
  {
    const int s0 = se[0];
#pragma unroll
    for (int c = 0; c < 4; ++c) {
      const int i = tid * 4 + c;
      alpha_sm[i] = Pi0[i] * B[(size_t)i * NOBS + s0];
    }
  }
  __syncthreads();

  // emission prefetch for step 1 (only publishing lanes need it: tid<32)
  float bv_next = 0.f;
  if (tid < OPB) bv_next = B[(size_t)i_mine * NOBS + se[1]];

  for (int t = 1; t < TSEQ; ++t) {
    const float bv  = bv_next;
    const int   buf = t & 1;
    if (tid < OPB) {
      const int tn = (t + 1 < TSEQ) ? (t + 1) : t;
      bv_next = B[(size_t)i_mine * NOBS + se[tn]];
    }

    // ---- dot over this thread's 128-long j-slice (alpha from LDS, A in regs)
    float a0 = 0.f, a1 = 0.f, a2 = 0.f, a3 = 0.f;
#define DOT(k) { const float4 av = *reinterpret_cast<const float4*>(&alpha_sm[jbase + 4 * k]); \
                 a0 = fmaf(Ar##k.x, av.x, a0); a1 = fmaf(Ar##k.y, av.y, a1); \
                 a2 = fmaf(Ar##k.z, av.z, a2); a3 = fmaf(Ar##k.w, av.w, a3); }
    A_LIST(DOT)
    float acc = (a0 + a1) + (a2 + a3);
    acc += __shfl_xor(acc, 32);        // combine the two half-wave j-slices
    if (lane < 32) red[buf][w][o] = acc;
    __syncthreads();   // the ONE barrier per step: red[buf] handoff to wave 0

    // ---- wave 0: finish reduction, apply emission, publish data then flag
    if (w == 0) {
      float s = 0.f;
#pragma unroll
      for (int ww = 0; ww < NTHR / 64; ++ww) s += red[buf][ww][o];
      if (lane < 32) {
        __hip_atomic_store(&aGd[(size_t)buf * NS + blk * OPB + o],
                           __float_as_uint(s * bv),
                           __ATOMIC_RELAXED, __HIP_MEMORY_SCOPE_AGENT);
      }
      asm volatile("s_waitcnt vmcnt(0)" ::: "memory");  // data at LLC before flag
      if (lane == 0) {
        __hip_atomic_store(&flags[blk * FSTR], (u32)t,
                           __ATOMIC_RELAXED, __HIP_MEMORY_SCOPE_AGENT);
      }
    }

    // ---- spin on the 8 source-block flags (lanes 0..7, one load each)
    {
      const int srcb = 8 * w + (lane & 7);
      for (;;) {
        u32 fv = 0u;
        if (lane < 8) {
          fv = __hip_atomic_load(&flags[srcb * FSTR],
                                 __ATOMIC_RELAXED, __HIP_MEMORY_SCOPE_AGENT);
        }
        const bool ok = (lane < 8) ? (fv >= (u32)t) : true;
        if (__ballot(ok) == ~0ull) break;
      }
    }

    // ---- one-shot gather of this wave's 256-float j-slice
    {
      const u64* dsrc = reinterpret_cast<const u64*>(
          aGd + (size_t)buf * NS + w * 256 + lane * 4);
      const u64 d0 = __hip_atomic_load(dsrc + 0, __ATOMIC_RELAXED, __HIP_MEMORY_SCOPE_AGENT);
      const u64 d1 = __hip_atomic_load(dsrc + 1, __ATOMIC_RELAXED, __HIP_MEMORY_SCOPE_AGENT);
      float4 v;
      v.x = __uint_as_float((u32)d0);
      v.y = __uint_as_float((u32)(d0 >> 32));
      v.z = __uint_as_float((u32)d1);
      v.w = __uint_as_float((u32)(d1 >> 32));
      *reinterpret_cast<float4*>(&alpha_sm[w * 256 + lane * 4]) = v;
    }
    // no barrier: next dot reads only this wave's own slice
  }

  // ---- final: -log(sum(alpha_{T-1})), block 0 only
  if (blk == 0) {
    __syncthreads();   // all waves' final gathers into alpha_sm
    float s = 0.f;
#pragma unroll
    for (int c = 0; c < 4; ++c) s += alpha_sm[4 * tid + c];
#pragma unroll
    for (int off = 32; off > 0; off >>= 1) s += __shfl_xor(s, off);
    if (lane == 0) red[0][w][0] = s;
    __syncthreads();
    if (tid == 0) {
      float S = 0.f;
#pragma unroll
      for (int ww = 0; ww < NTHR / 64; ++ww) S += red[0][ww][0];
      out[0] = -logf(S);
    }
  }
}

extern "C" void kernel_launch(void* const* d_in, const int* in_sizes, int n_in,
                              void* d_out, int out_size, void* d_ws, size_t ws_size,
                              hipStream_t stream) {
  const float* Pi0 = (const float*)d_in[0];
  const float* A   = (const float*)d_in[1];
  const float* B   = (const float*)d_in[2];
  const int*   se  = (const int*)d_in[3];
  float*       out = (float*)d_out;

  // ws layout: aGd = u32[2][NS] alpha payload (16 KiB) @0;
  //            flags = u32[NBLK*FSTR] (8 KiB) @16 KiB
  u32* aGd   = (u32*)d_ws;
  u32* flags = (u32*)((char*)d_ws + 16384);

  init_ws_kernel<<<1, 256, 0, stream>>>(flags);              // zero all flags
  hmm_forward_kernel<<<NBLK, NTHR, 0, stream>>>(Pi0, A, B, se, out, aGd, flags);
}